// Round 6
// baseline (94.596 us; speedup 1.0000x reference)
//
#include <hip/hip_runtime.h>
#include <math.h>

#define B_   32
#define T_   4096
#define TP_  1024
#define CH_  330
#define CH2_ 165    // float2 channels per frame
#define Z_   128
#define L_   128    // chunk length
#define W_   128    // warmup steps (0.95^128 ~ 1.4e-3 decay; measured absmax 0.0156 << 0.108)
#define C_   32     // T_/L_
#define G_   32     // superstep: 32 f2 loads forced in flight (64 VGPR)

typedef float f2 __attribute__((ext_vector_type(2)));

__constant__ float c_mass[55] = {
  0.1117f, 0.1416f, 0.1416f, 0.1633f, 0.0433f, 0.0433f, 0.1596f, 0.0137f,
  0.0137f, 0.1596f, 0.0137f, 0.0137f, 0.035f,  0.008f,  0.008f,  0.0694f,
  0.0271f, 0.0271f, 0.0162f, 0.0162f, 0.0061f, 0.0061f, 0.007f,  0.001f,
  0.001f,
  0.0004f,0.0004f,0.0004f,0.0004f,0.0004f,0.0004f,0.0004f,0.0004f,0.0004f,0.0004f,
  0.0004f,0.0004f,0.0004f,0.0004f,0.0004f,0.0004f,0.0004f,0.0004f,0.0004f,0.0004f,
  0.0004f,0.0004f,0.0004f,0.0004f,0.0004f,0.0004f,0.0004f,0.0004f,0.0004f,0.0004f
};

// scale[b,tp] = 0.5*(1-psi)*(1+mean(exp(logvar))) ; one wave per row
__global__ __launch_bounds__(256) void scale_kernel(const float* __restrict__ psi,
                                                    const float* __restrict__ logvar,
                                                    float* __restrict__ scale) {
  int row  = blockIdx.x * 4 + (threadIdx.x >> 6);   // 4 waves/block, 1 row/wave
  int lane = threadIdx.x & 63;
  f2 v = reinterpret_cast<const f2*>(logvar + (size_t)row * Z_)[lane];
  float e = __expf(v.x) + __expf(v.y);
  #pragma unroll
  for (int off = 32; off > 0; off >>= 1) e += __shfl_down(e, off, 64);
  if (lane == 0) {
    scale[row] = 0.5f * (1.0f - psi[row]) * (1.0f + e * (1.0f / 128.0f));
  }
}

// One block per (chunk, batch). Thread = one float2 (2 adjacent channels, same joint).
__global__ __launch_bounds__(192) void smooth_kernel(const float* __restrict__ x,
                                                     const float* __restrict__ scale,
                                                     const float* __restrict__ init,
                                                     float* __restrict__ out) {
  const int c   = blockIdx.x;
  const int b   = blockIdx.y;
  const int tid = threadIdx.x;

  __shared__ float s_scale[(L_ + W_) / 4];

  const int t0     = c * L_;
  const int tw     = (c == 0) ? 0 : (t0 - W_);
  const int nsteps = t0 + L_ - tw;            // 128 (c==0) or 256
  const int nsc    = nsteps >> 2;
  for (int i = tid; i < nsc; i += 192) s_scale[i] = scale[b * TP_ + (tw >> 2) + i];
  __syncthreads();
  if (tid >= CH2_) return;

  // channels (2*tid, 2*tid+1) share joint tid/3 (6 floats/joint, 6 even)
  const float shape = fmaxf(sqrtf(c_mass[tid / 3] * (1.0f / 0.1633f)), 0.1f);

  f2 st;
  if (c == 0) st = reinterpret_cast<const f2*>(init)[(size_t)b * CH2_ + tid];
  else        st = (f2)(0.0f);

  const f2* xp = reinterpret_cast<const f2*>(x) + ((size_t)b * T_ + tw) * CH2_ + tid;
  f2*       op = reinterpret_cast<f2*>(out)     + ((size_t)b * T_ + t0) * CH2_ + tid;

  f2 buf[G_];

  // One superstep = issue ALL 32 loads (sched_barrier pins them before any
  // use -> 64 VGPRs of loads in flight), then 32 recurrence steps (+stores).
  auto super = [&](int gt, bool emit) {
    #pragma unroll
    for (int k = 0; k < G_; ++k) buf[k] = xp[k * CH2_];
    xp += G_ * CH2_;
    __builtin_amdgcn_sched_barrier(0);
    float ta[G_ / 4];
    #pragma unroll
    for (int q = 0; q < G_ / 4; ++q)
      ta[q] = fminf(fmaxf(s_scale[gt * (G_ / 4) + q] * shape, 0.0f), 0.95f);
    #pragma unroll
    for (int k = 0; k < G_; ++k) {
      float tq = ta[k >> 2];
      st.x = fmaf(tq, st.x - buf[k].x, buf[k].x);   // (1-tau)*x + tau*state
      st.y = fmaf(tq, st.y - buf[k].y, buf[k].y);
      if (emit) __builtin_nontemporal_store(st, &op[k * CH2_]);
    }
    if (emit) op += G_ * CH2_;
  };

  int gt = 0;
  if (c != 0) {
    #pragma unroll
    for (int g = 0; g < W_ / G_; ++g) super(gt++, false);   // warmup (L3-hit reads)
  }
  #pragma unroll
  for (int g = 0; g < L_ / G_; ++g) super(gt++, true);      // emit chunk
}

extern "C" void kernel_launch(void* const* d_in, const int* in_sizes, int n_in,
                              void* d_out, int out_size, void* d_ws, size_t ws_size,
                              hipStream_t stream) {
  const float* poses  = (const float*)d_in[0];  // (32,4096,55,6)
  const float* psi    = (const float*)d_in[1];  // (32,1024)
  const float* logvar = (const float*)d_in[2];  // (32,1024,128)
  const float* init   = (const float*)d_in[3];  // (32,55,6)
  float* out   = (float*)d_out;                 // (32,4096,55,6)
  float* scale = (float*)d_ws;                  // 32*1024 floats = 128 KB

  scale_kernel<<<dim3(B_ * TP_ / 4), 256, 0, stream>>>(psi, logvar, scale);
  smooth_kernel<<<dim3(C_, B_), 192, 0, stream>>>(poses, scale, init, out);
}

// Round 7
// 90.477 us; speedup vs baseline: 1.0455x; 1.0455x over previous
//
#include <hip/hip_runtime.h>
#include <math.h>

#define B_   32
#define T_   4096
#define TP_  1024
#define CH_  330
#define CH2_ 165    // float2 channels per frame
#define Z_   128
#define L_   256    // emit length per block (read overhead (W+L)/L = 1.5)
#define W_   128    // warmup steps (0.95^128 ~ 1.4e-3 decay; measured absmax 0.0156 << 0.108)
#define C_   16     // T_/L_
#define G_   32     // superstep: 32 f2 loads in flight (64 VGPR)

typedef float f2 __attribute__((ext_vector_type(2)));

__constant__ float c_mass[55] = {
  0.1117f, 0.1416f, 0.1416f, 0.1633f, 0.0433f, 0.0433f, 0.1596f, 0.0137f,
  0.0137f, 0.1596f, 0.0137f, 0.0137f, 0.035f,  0.008f,  0.008f,  0.0694f,
  0.0271f, 0.0271f, 0.0162f, 0.0162f, 0.0061f, 0.0061f, 0.007f,  0.001f,
  0.001f,
  0.0004f,0.0004f,0.0004f,0.0004f,0.0004f,0.0004f,0.0004f,0.0004f,0.0004f,0.0004f,
  0.0004f,0.0004f,0.0004f,0.0004f,0.0004f,0.0004f,0.0004f,0.0004f,0.0004f,0.0004f,
  0.0004f,0.0004f,0.0004f,0.0004f,0.0004f,0.0004f,0.0004f,0.0004f,0.0004f,0.0004f
};

// scale[b,tp] = 0.5*(1-psi)*(1+mean(exp(logvar))) ; one wave per row
__global__ __launch_bounds__(256) void scale_kernel(const float* __restrict__ psi,
                                                    const float* __restrict__ logvar,
                                                    float* __restrict__ scale) {
  int row  = blockIdx.x * 4 + (threadIdx.x >> 6);   // 4 waves/block, 1 row/wave
  int lane = threadIdx.x & 63;
  f2 v = reinterpret_cast<const f2*>(logvar + (size_t)row * Z_)[lane];
  float e = __expf(v.x) + __expf(v.y);
  #pragma unroll
  for (int off = 32; off > 0; off >>= 1) e += __shfl_down(e, off, 64);
  if (lane == 0) {
    scale[row] = 0.5f * (1.0f - psi[row]) * (1.0f + e * (1.0f / 128.0f));
  }
}

// One block per (chunk, batch). Thread = one float2 (2 adjacent channels, same joint).
__global__ __launch_bounds__(192, 1) void smooth_kernel(const float* __restrict__ x,
                                                        const float* __restrict__ scale,
                                                        const float* __restrict__ init,
                                                        float* __restrict__ out) {
  const int c   = blockIdx.x;
  const int b   = blockIdx.y;
  const int tid = threadIdx.x;

  __shared__ float s_scale[(L_ + W_) / 4];

  const int t0     = c * L_;
  const int tw     = (c == 0) ? 0 : (t0 - W_);
  const int nsteps = t0 + L_ - tw;            // 256 (c==0) or 384
  const int nsc    = nsteps >> 2;
  for (int i = tid; i < nsc; i += 192) s_scale[i] = scale[b * TP_ + (tw >> 2) + i];
  __syncthreads();
  if (tid >= CH2_) return;

  // channels (2*tid, 2*tid+1) share joint tid/3 (6 floats/joint, 6 even)
  const float shape = fmaxf(sqrtf(c_mass[tid / 3] * (1.0f / 0.1633f)), 0.1f);

  f2 st;
  if (c == 0) st = reinterpret_cast<const f2*>(init)[(size_t)b * CH2_ + tid];
  else        st = (f2)(0.0f);

  const f2* xp = reinterpret_cast<const f2*>(x) + ((size_t)b * T_ + tw) * CH2_ + tid;
  f2*       op = reinterpret_cast<f2*>(out)     + ((size_t)b * T_ + t0) * CH2_ + tid;

  f2 buf[G_];

  // One superstep = issue ALL 32 loads (sched_barrier pins them before any
  // use -> 64 VGPRs of loads in flight), then 32 recurrence steps (+stores).
  auto super = [&](int gt, bool emit) {
    #pragma unroll
    for (int k = 0; k < G_; ++k) buf[k] = xp[k * CH2_];
    xp += G_ * CH2_;
    __builtin_amdgcn_sched_barrier(0);
    float ta[G_ / 4];
    #pragma unroll
    for (int q = 0; q < G_ / 4; ++q)
      ta[q] = fminf(fmaxf(s_scale[gt * (G_ / 4) + q] * shape, 0.0f), 0.95f);
    #pragma unroll
    for (int k = 0; k < G_; ++k) {
      float tq = ta[k >> 2];
      st.x = fmaf(tq, st.x - buf[k].x, buf[k].x);   // (1-tau)*x + tau*state
      st.y = fmaf(tq, st.y - buf[k].y, buf[k].y);
      if (emit) __builtin_nontemporal_store(st, &op[k * CH2_]);
    }
    if (emit) op += G_ * CH2_;
  };

  int gt = 0;
  if (c != 0) {
    #pragma unroll
    for (int g = 0; g < W_ / G_; ++g) super(gt++, false);   // warmup (L3-hit reads)
  }
  #pragma unroll
  for (int g = 0; g < L_ / G_; ++g) super(gt++, true);      // emit chunk
}

extern "C" void kernel_launch(void* const* d_in, const int* in_sizes, int n_in,
                              void* d_out, int out_size, void* d_ws, size_t ws_size,
                              hipStream_t stream) {
  const float* poses  = (const float*)d_in[0];  // (32,4096,55,6)
  const float* psi    = (const float*)d_in[1];  // (32,1024)
  const float* logvar = (const float*)d_in[2];  // (32,1024,128)
  const float* init   = (const float*)d_in[3];  // (32,55,6)
  float* out   = (float*)d_out;                 // (32,4096,55,6)
  float* scale = (float*)d_ws;                  // 32*1024 floats = 128 KB

  scale_kernel<<<dim3(B_ * TP_ / 4), 256, 0, stream>>>(psi, logvar, scale);
  smooth_kernel<<<dim3(C_, B_), 192, 0, stream>>>(poses, scale, init, out);
}

// Round 8
// 75.738 us; speedup vs baseline: 1.2490x; 1.1946x over previous
//
#include <hip/hip_runtime.h>
#include <math.h>

#define B_   32
#define T_   4096
#define TP_  1024
#define CH_  330
#define CH2_ 165
#define Z_   128
#define L_   256    // emit steps per block
#define W_   128    // warmup steps (0.95^128 ~ 1.4e-3; measured absmax 0.0156 << 0.108)
#define C_   16     // T_/L_
#define GRP_ 16     // frames per LDS tile
#define VPG_ (GRP_*CH_/4)   // 1320 valid f4 per tile
#define RND_ 6              // ceil(1320/256) stage rounds
#define BUFV_ (RND_*256)    // 1536 f4 slots (padded)

typedef float f2 __attribute__((ext_vector_type(2)));
typedef float f4 __attribute__((ext_vector_type(4)));

__constant__ float c_mass[55] = {
  0.1117f, 0.1416f, 0.1416f, 0.1633f, 0.0433f, 0.0433f, 0.1596f, 0.0137f,
  0.0137f, 0.1596f, 0.0137f, 0.0137f, 0.035f,  0.008f,  0.008f,  0.0694f,
  0.0271f, 0.0271f, 0.0162f, 0.0162f, 0.0061f, 0.0061f, 0.007f,  0.001f,
  0.001f,
  0.0004f,0.0004f,0.0004f,0.0004f,0.0004f,0.0004f,0.0004f,0.0004f,0.0004f,0.0004f,
  0.0004f,0.0004f,0.0004f,0.0004f,0.0004f,0.0004f,0.0004f,0.0004f,0.0004f,0.0004f,
  0.0004f,0.0004f,0.0004f,0.0004f,0.0004f,0.0004f,0.0004f,0.0004f,0.0004f,0.0004f
};

// scale[b,tp] = 0.5*(1-psi)*(1+mean(exp(logvar))) ; one wave per row
__global__ __launch_bounds__(256) void scale_kernel(const float* __restrict__ psi,
                                                    const float* __restrict__ logvar,
                                                    float* __restrict__ scale) {
  int row  = blockIdx.x * 4 + (threadIdx.x >> 6);
  int lane = threadIdx.x & 63;
  f2 v = reinterpret_cast<const f2*>(logvar + (size_t)row * Z_)[lane];
  float e = __expf(v.x) + __expf(v.y);
  #pragma unroll
  for (int off = 32; off > 0; off >>= 1) e += __shfl_down(e, off, 64);
  if (lane == 0) {
    scale[row] = 0.5f * (1.0f - psi[row]) * (1.0f + e * (1.0f / 128.0f));
  }
}

// One block per (chunk, batch). All global traffic is aligned 16B/lane via LDS tiles.
__global__ __launch_bounds__(256) void smooth_kernel(const float* __restrict__ x,
                                                     const float* __restrict__ scale,
                                                     const float* __restrict__ init,
                                                     float* __restrict__ out) {
  const int c   = blockIdx.x;
  const int b   = blockIdx.y;
  const int tid = threadIdx.x;

  __shared__ f4 xbuf[2][BUFV_];   // 2 x 24576 B
  __shared__ f4 obuf[BUFV_];      // 24576 B
  __shared__ float s_scale[(L_ + W_) / 4];

  const int t0     = c * L_;
  const int tw     = (c == 0) ? 0 : (t0 - W_);     // multiple of 128 -> 16B-aligned tiles
  const int nsteps = t0 + L_ - tw;                  // 256 or 384
  const int ng     = nsteps / GRP_;                 // 16 or 24
  const int gw     = (c == 0) ? 0 : (W_ / GRP_);    // 0 or 8 warmup groups
  for (int i = tid; i < (nsteps >> 2); i += 256) s_scale[i] = scale[b * TP_ + (tw >> 2) + i];

  const f4* xg = reinterpret_cast<const f4*>(x   + ((size_t)b * T_ + tw) * CH_);
  f4*       og = reinterpret_cast<f4*>(out + ((size_t)b * T_ + t0) * CH_);

  const int k = tid;              // f2-channel id if < 165 (pair shares joint k/3)
  float shape = 0.0f;
  f2 st = (f2)(0.0f);
  if (k < CH2_) {
    shape = fmaxf(sqrtf(c_mass[k / 3] * (1.0f / 0.1633f)), 0.1f);
    if (c == 0) st = reinterpret_cast<const f2*>(init)[(size_t)b * CH2_ + k];
  }

  // prologue: stage tile 0
  {
    f4 v[RND_];
    #pragma unroll
    for (int r = 0; r < RND_; ++r) { int i = r * 256 + tid; v[r] = xg[(i < VPG_) ? i : 0]; }
    #pragma unroll
    for (int r = 0; r < RND_; ++r) xbuf[0][r * 256 + tid] = v[r];
  }

  int cur = 0;
  for (int g = 0; g < ng; ++g) {
    __syncthreads();                       // xbuf[cur] staged, obuf free
    // T14: issue next tile's loads to regs BEFORE compute (latency hides under compute)
    f4 v[RND_];
    const bool more = (g + 1) < ng;
    if (more) {
      const f4* src = xg + (size_t)(g + 1) * VPG_;
      #pragma unroll
      for (int r = 0; r < RND_; ++r) { int i = r * 256 + tid; v[r] = src[(i < VPG_) ? i : 0]; }
    }
    // compute 16 steps from xbuf[cur] -> obuf (LDS only)
    const bool emit = g >= gw;
    if (k < CH2_) {
      const f2* xl = reinterpret_cast<const f2*>(&xbuf[cur][0]);
      f2*       ol = reinterpret_cast<f2*>(&obuf[0]);
      const int sb = g * (GRP_ / 4);
      #pragma unroll
      for (int q = 0; q < GRP_ / 4; ++q) {
        float tau = fminf(fmaxf(s_scale[sb + q] * shape, 0.0f), 0.95f);
        #pragma unroll
        for (int u = 0; u < 4; ++u) {
          int t = q * 4 + u;
          f2 xv = xl[t * CH2_ + k];
          st.x = fmaf(tau, st.x - xv.x, xv.x);   // (1-tau)*x + tau*state
          st.y = fmaf(tau, st.y - xv.y, xv.y);
          if (emit) ol[t * CH2_ + k] = st;
        }
      }
    }
    // write staged regs into the other xbuf
    if (more) {
      #pragma unroll
      for (int r = 0; r < RND_; ++r) xbuf[cur ^ 1][r * 256 + tid] = v[r];
    }
    __syncthreads();                       // obuf complete, xbuf[nxt] written
    if (emit) {
      f4* dst = og + (size_t)(g - gw) * VPG_;
      #pragma unroll
      for (int r = 0; r < RND_; ++r) {
        int i = r * 256 + tid;
        if (i < VPG_) __builtin_nontemporal_store(obuf[i], &dst[i]);
      }
    }
    cur ^= 1;
  }
}

extern "C" void kernel_launch(void* const* d_in, const int* in_sizes, int n_in,
                              void* d_out, int out_size, void* d_ws, size_t ws_size,
                              hipStream_t stream) {
  const float* poses  = (const float*)d_in[0];  // (32,4096,55,6)
  const float* psi    = (const float*)d_in[1];  // (32,1024)
  const float* logvar = (const float*)d_in[2];  // (32,1024,128)
  const float* init   = (const float*)d_in[3];  // (32,55,6)
  float* out   = (float*)d_out;                 // (32,4096,55,6)
  float* scale = (float*)d_ws;                  // 32*1024 floats = 128 KB

  scale_kernel<<<dim3(B_ * TP_ / 4), 256, 0, stream>>>(psi, logvar, scale);
  smooth_kernel<<<dim3(C_, B_), 256, 0, stream>>>(poses, scale, init, out);
}